// Round 6
// baseline (189.650 us; speedup 1.0000x reference)
//
#include <hip/hip_runtime.h>

// MTFNet: N=8, C=8, H=W=256, L=11, SF=2, h=w=128
// Pipeline:
//  K0: xpad[nc][256][272] = column-reflect-padded x (halo 8 each side)
//  K1: E2[n][c'][p] = (blur(x,k) - y), flat reinterpret (p*8+c' = flat(C,h,w)); 8 ps/thread
//  K2: G[n][ki*11+kj][c] = (1/16384) * sum_p xpad window * E2; 8 ps/thread
//  K3: per-n pronet (9 convs) on G_K = k - 0.1*gamma*G (flat), + normalize (v3)
// Accounting (R1-R5): harness resets ~130-140us of dur_us (268MB ws poison + ~25
// restore dispatches) — controllable part is only the 4 kernels (~35-40us).

__device__ __forceinline__ int refl(int m) {
    m = (m < 0) ? -m : m;
    return (m > 255) ? (510 - m) : m;
}

#define XPROW 272   // 256 + 8 halo each side

// ---------------- K0: column-pad x with reflection ----------------
__global__ __launch_bounds__(256) void pad_kernel(
        const float* __restrict__ x, float* __restrict__ xp) {
    int bid = blockIdx.x;
    int chunk = bid & 3;
    int nc = bid >> 2;
    int team = threadIdx.x >> 6;
    int lane = threadIdx.x & 63;
    const float* xb = x + nc * 65536;
    float* xpb = xp + nc * (256 * XPROW);
    for (int it = 0; it < 16; ++it) {
        int row = chunk * 64 + it * 4 + team;
        const float* src = xb + row * 256;
        float* dst = xpb + row * XPROW + 8;
        float4 v = reinterpret_cast<const float4*>(src)[lane];
        reinterpret_cast<float4*>(dst)[lane] = v;
        if (lane < 8) {
            dst[-1 - lane] = src[1 + lane];
        } else if (lane < 16) {
            int j = lane - 8;
            dst[256 + j] = src[254 - j];
        }
    }
}

// ---------------- K1: blur, 8 outputs/thread ----------------
// grid = 64 nc * 8 rowblk = 512 blocks; 256 threads = (row 0..15) x (psg 0..15)
__global__ __launch_bounds__(256) void blur_kernel(
        const float* __restrict__ xp, const float* __restrict__ y,
        const float* __restrict__ kk, float* __restrict__ E2) {
    __shared__ float kl[121];
    int bid = blockIdx.x;
    int rowblk = bid & 7;
    int nc = bid >> 3;
    int t = threadIdx.x;
    if (t < 121) kl[t] = kk[nc * 121 + t];
    __syncthreads();
    int r = rowblk * 16 + (t >> 4);    // output row 0..127
    int ps0 = (t & 15) * 8;            // output col base (mult of 8)
    const float* xb = xp + nc * (256 * XPROW);
    float acc[8];
    #pragma unroll
    for (int ps = 0; ps < 8; ++ps) acc[ps] = 0.f;
    #pragma unroll
    for (int i = 0; i < 11; ++i) {
        int iy = refl(2 * r - 5 + i);
        // stored window [2ps0 .. 2ps0+31] covers needed [2ps0+3 .. 2ps0+27]
        const float4* row4 = reinterpret_cast<const float4*>(xb + iy * XPROW + 2 * ps0);
        float w[32];
        #pragma unroll
        for (int q = 0; q < 8; ++q) {
            float4 v = row4[q];
            w[4 * q] = v.x; w[4 * q + 1] = v.y; w[4 * q + 2] = v.z; w[4 * q + 3] = v.w;
        }
        #pragma unroll
        for (int j = 0; j < 11; ++j) {
            float kv = kl[i * 11 + j];
            #pragma unroll
            for (int ps = 0; ps < 8; ++ps)
                acc[ps] = fmaf(w[2 * ps + j + 3], kv, acc[ps]);
        }
    }
    int n = nc >> 3;
    int o = nc * 16384 + r * 128 + ps0;          // flat [N][C][128][128]
    float4 yv0 = *reinterpret_cast<const float4*>(y + o);
    float4 yv1 = *reinterpret_cast<const float4*>(y + o + 4);
    float e[8] = {acc[0] - yv0.x, acc[1] - yv0.y, acc[2] - yv0.z, acc[3] - yv0.w,
                  acc[4] - yv1.x, acc[5] - yv1.y, acc[6] - yv1.z, acc[7] - yv1.w};
    // qn multiple of 8 -> these 8 flat elems are (p = qn>>3, c' = 0..7)
    int qn = o - n * 131072;
    int p = qn >> 3;
    float* eb = E2 + n * 131072 + p;
    #pragma unroll
    for (int qq = 0; qq < 8; ++qq)
        eb[qq * 16384] = e[qq];
}

// ---------------- K2: G contraction, 8 ps/thread ----------------
// grid = 64 (n*c) * 11 (ki) = 704 blocks; 256 threads = (prg 0..15) x (psg 0..15)
__global__ __launch_bounds__(256) void grad_kernel(
        const float* __restrict__ xp, const float* __restrict__ E2,
        float* __restrict__ G) {
    int bid = blockIdx.x;
    int ki = bid % 11;
    int nc = bid / 11;
    int n = nc >> 3, c = nc & 7;
    const float* xb = xp + nc * (256 * XPROW);
    const float* Eb = E2 + n * 131072 + c * 16384;
    int t = threadIdx.x;
    int ps0 = (t & 15) * 8;
    int prg = t >> 4;
    float acc[11];
    #pragma unroll
    for (int j = 0; j < 11; ++j) acc[j] = 0.f;
    #pragma unroll
    for (int it = 0; it < 8; ++it) {
        int pr = prg + (it << 4);
        int iy = refl(ki + 2 * pr - 5);
        float4 ev0 = *reinterpret_cast<const float4*>(Eb + pr * 128 + ps0);
        float4 ev1 = *reinterpret_cast<const float4*>(Eb + pr * 128 + ps0 + 4);
        float e[8] = {ev0.x, ev0.y, ev0.z, ev0.w, ev1.x, ev1.y, ev1.z, ev1.w};
        const float4* row4 = reinterpret_cast<const float4*>(xb + iy * XPROW + 2 * ps0);
        float w[32];
        #pragma unroll
        for (int q = 0; q < 8; ++q) {
            float4 v = row4[q];
            w[4 * q] = v.x; w[4 * q + 1] = v.y; w[4 * q + 2] = v.z; w[4 * q + 3] = v.w;
        }
        #pragma unroll
        for (int j = 0; j < 11; ++j) {
            float v = acc[j];
            #pragma unroll
            for (int ps = 0; ps < 8; ++ps)
                v = fmaf(w[2 * ps + j + 3], e[ps], v);
            acc[j] = v;
        }
    }
    __shared__ float part[4][11];
    int lane = t & 63, wid = t >> 6;
    #pragma unroll
    for (int j = 0; j < 11; ++j) {
        float v = acc[j];
        #pragma unroll
        for (int off = 32; off > 0; off >>= 1)
            v += __shfl_down(v, off, 64);
        if (lane == 0) part[wid][j] = v;
    }
    __syncthreads();
    if (t < 11) {
        float s = part[0][t] + part[1][t] + part[2][t] + part[3][t];
        G[n * 968 + (ki * 11 + t) * 8 + c] = s * (1.0f / 16384.0f);
    }
}

// ---------------- Fallback kernels (R3, scalar loads, known-good) ----------
__global__ __launch_bounds__(256) void blur_kernel_ref(
        const float* __restrict__ x, const float* __restrict__ y,
        const float* __restrict__ kk, float* __restrict__ E2) {
    __shared__ float kl[121];
    int bid = blockIdx.x;
    int rowblk = bid & 15;
    int nc = bid >> 4;
    int t = threadIdx.x;
    if (t < 121) kl[t] = kk[nc * 121 + t];
    __syncthreads();
    int r = rowblk * 8 + (t >> 5);
    int ps0 = (t & 31) * 4;
    const float* xb = x + nc * 65536;
    float a0 = 0.f, a1 = 0.f, a2 = 0.f, a3 = 0.f;
    int cb = 2 * ps0 - 5;
    #pragma unroll
    for (int i = 0; i < 11; ++i) {
        int iy = refl(2 * r - 5 + i);
        const float* row = xb + iy * 256;
        float c[17];
        #pragma unroll
        for (int u = 0; u < 17; ++u) c[u] = row[refl(cb + u)];
        #pragma unroll
        for (int j = 0; j < 11; ++j) {
            float kv = kl[i * 11 + j];
            a0 = fmaf(c[j], kv, a0);
            a1 = fmaf(c[j + 2], kv, a1);
            a2 = fmaf(c[j + 4], kv, a2);
            a3 = fmaf(c[j + 6], kv, a3);
        }
    }
    int n = nc >> 3;
    int o = nc * 16384 + r * 128 + ps0;
    float4 yv = *reinterpret_cast<const float4*>(y + o);
    float e[4] = {a0 - yv.x, a1 - yv.y, a2 - yv.z, a3 - yv.w};
    int qn = o - n * 131072;
    int p = qn >> 3;
    int cbase = qn & 7;
    float* eb = E2 + n * 131072 + p;
    #pragma unroll
    for (int qq = 0; qq < 4; ++qq)
        eb[(cbase + qq) * 16384] = e[qq];
}

__global__ __launch_bounds__(256) void grad_kernel_ref(
        const float* __restrict__ x, const float* __restrict__ E2,
        float* __restrict__ G) {
    int bid = blockIdx.x;
    int ki = bid % 11;
    int nc = bid / 11;
    int n = nc >> 3, c = nc & 7;
    const float* xb = x + nc * 65536;
    const float* Eb = E2 + n * 131072 + c * 16384;
    int t = threadIdx.x;
    int ps0 = (t & 31) * 4;
    int pr0 = t >> 5;
    int cb = 2 * ps0 - 5;
    float acc[11];
    #pragma unroll
    for (int j = 0; j < 11; ++j) acc[j] = 0.f;
    for (int it = 0; it < 16; ++it) {
        int pr = pr0 + (it << 3);
        int iy = refl(ki + 2 * pr - 5);
        const float* row = xb + iy * 256;
        float cbuf[17];
        #pragma unroll
        for (int u = 0; u < 17; ++u) cbuf[u] = row[refl(cb + u)];
        float4 ev = *reinterpret_cast<const float4*>(Eb + pr * 128 + ps0);
        #pragma unroll
        for (int j = 0; j < 11; ++j) {
            float v = acc[j];
            v = fmaf(cbuf[j], ev.x, v);
            v = fmaf(cbuf[j + 2], ev.y, v);
            v = fmaf(cbuf[j + 4], ev.z, v);
            v = fmaf(cbuf[j + 6], ev.w, v);
            acc[j] = v;
        }
    }
    __shared__ float part[4][11];
    int lane = t & 63, wid = t >> 6;
    #pragma unroll
    for (int j = 0; j < 11; ++j) {
        float v = acc[j];
        #pragma unroll
        for (int off = 32; off > 0; off >>= 1)
            v += __shfl_down(v, off, 64);
        if (lane == 0) part[wid][j] = v;
    }
    __syncthreads();
    if (t < 11) {
        float s = part[0][t] + part[1][t] + part[2][t] + part[3][t];
        G[n * 968 + (ki * 11 + t) * 8 + c] = s * (1.0f / 16384.0f);
    }
}

// ---------------- K3: pronet v3 ----------------
struct PArgs {
    const float* W[9];
    const float* B[9];
    const float* k;
    const float* gamma;
    const float* G;
    float* out;
};

#define PLSTRIDE 20
#define WSTRIDE 12

__global__ __launch_bounds__(384) void pronet_kernel(PArgs pa) {
    __shared__ __align__(16) float P0[8 * 13 * PLSTRIDE];
    __shared__ __align__(16) float P1[8 * 13 * PLSTRIDE];
    __shared__ float G2[968];
    __shared__ float F[968];
    __shared__ __align__(16) float red[3 * 88 * WSTRIDE];
    __shared__ __align__(16) float wts[9 * 64 * WSTRIDE];
    __shared__ float bs[9 * 8];
    __shared__ float rowsum[88];
    __shared__ float inv[8];

    int n = blockIdx.x;
    int t = threadIdx.x;

    #pragma unroll
    for (int widx = 0; widx < 9; ++widx) {
        const float* wsrc = pa.W[widx];
        for (int i = t; i < 576; i += 384) {
            int oc = i / 9, q = i - oc * 9;
            wts[(widx * 64 + oc) * WSTRIDE + q] = wsrc[i];
        }
        if (t < 8) bs[widx * 8 + t] = pa.B[widx][t];
    }
    for (int i = t; i < 8 * 13 * PLSTRIDE; i += 384) { P0[i] = 0.f; P1[i] = 0.f; }
    __syncthreads();

    float gm = pa.gamma[0] * 0.1f;
    for (int o = t; o < 968; o += 384) {
        float v = pa.k[n * 968 + o] - gm * pa.G[n * 968 + o];
        G2[o] = v;
        int co = o / 121, rem = o - co * 121;
        int yy = rem / 11, xx = rem - yy * 11;
        P0[(co * 13 + yy + 1) * PLSTRIDE + xx + 1] = v;
    }

    bool active = t < 352;
    int quarter = t / 88;
    int id = t - quarter * 88;
    int co = id / 11, yy = id - co * 11;
    int ci0 = quarter * 2;

    auto do_conv = [&](const float* Pin, int widx, int mode) {
        __syncthreads();
        float acc[12];
        if (active) {
            #pragma unroll
            for (int xx = 0; xx < 12; ++xx) acc[xx] = 0.f;
            #pragma unroll
            for (int cq = 0; cq < 2; ++cq) {
                int ci = ci0 + cq;
                const float4* wp4 = reinterpret_cast<const float4*>(
                    &wts[(widx * 64 + co * 8 + ci) * WSTRIDE]);
                float4 w0 = wp4[0], w1 = wp4[1], w2 = wp4[2];
                float wv[9] = {w0.x, w0.y, w0.z, w0.w, w1.x, w1.y, w1.z, w1.w, w2.x};
                float r[3][13];
                #pragma unroll
                for (int dy = 0; dy < 3; ++dy) {
                    const float* row = Pin + (ci * 13 + yy + dy) * PLSTRIDE;
                    float4 a = *reinterpret_cast<const float4*>(row);
                    float4 b = *reinterpret_cast<const float4*>(row + 4);
                    float4 c = *reinterpret_cast<const float4*>(row + 8);
                    r[dy][0] = a.x;  r[dy][1] = a.y;  r[dy][2]  = a.z;  r[dy][3]  = a.w;
                    r[dy][4] = b.x;  r[dy][5] = b.y;  r[dy][6]  = b.z;  r[dy][7]  = b.w;
                    r[dy][8] = c.x;  r[dy][9] = c.y;  r[dy][10] = c.z;  r[dy][11] = c.w;
                    r[dy][12] = row[12];
                }
                #pragma unroll
                for (int xx = 0; xx < 11; ++xx) {
                    float v = acc[xx];
                    v = fmaf(r[0][xx],     wv[0], v);
                    v = fmaf(r[0][xx + 1], wv[1], v);
                    v = fmaf(r[0][xx + 2], wv[2], v);
                    v = fmaf(r[1][xx],     wv[3], v);
                    v = fmaf(r[1][xx + 1], wv[4], v);
                    v = fmaf(r[1][xx + 2], wv[5], v);
                    v = fmaf(r[2][xx],     wv[6], v);
                    v = fmaf(r[2][xx + 1], wv[7], v);
                    v = fmaf(r[2][xx + 2], wv[8], v);
                    acc[xx] = v;
                }
            }
            if (quarter != 0) {
                float4* rp = reinterpret_cast<float4*>(
                    &red[((quarter - 1) * 88 + id) * WSTRIDE]);
                rp[0] = make_float4(acc[0], acc[1], acc[2],  acc[3]);
                rp[1] = make_float4(acc[4], acc[5], acc[6],  acc[7]);
                rp[2] = make_float4(acc[8], acc[9], acc[10], acc[11]);
            }
        }
        __syncthreads();
        if (active && quarter == 0) {
            float b = bs[widx * 8 + co];
            float oth[12];
            #pragma unroll
            for (int pq = 0; pq < 3; ++pq) {
                const float4* rp = reinterpret_cast<const float4*>(
                    &red[(pq * 88 + id) * WSTRIDE]);
                float4 v0 = rp[0], v1 = rp[1], v2 = rp[2];
                if (pq == 0) {
                    oth[0] = v0.x; oth[1] = v0.y; oth[2]  = v0.z; oth[3]  = v0.w;
                    oth[4] = v1.x; oth[5] = v1.y; oth[6]  = v1.z; oth[7]  = v1.w;
                    oth[8] = v2.x; oth[9] = v2.y; oth[10] = v2.z; oth[11] = v2.w;
                } else {
                    oth[0] += v0.x; oth[1] += v0.y; oth[2]  += v0.z; oth[3]  += v0.w;
                    oth[4] += v1.x; oth[5] += v1.y; oth[6]  += v1.z; oth[7]  += v1.w;
                    oth[8] += v2.x; oth[9] += v2.y; oth[10] += v2.z; oth[11] += v2.w;
                }
            }
            #pragma unroll
            for (int xx = 0; xx < 11; ++xx) {
                float v = acc[xx] + oth[xx] + b;
                int pidx = (co * 13 + yy + 1) * PLSTRIDE + xx + 1;
                if (mode == 0) {
                    P1[pidx] = fmaxf(v, 0.f);
                } else if (mode == 1) {
                    float p = P0[pidx];
                    P0[pidx] = fmaxf(fmaf(0.1f, v, p), 0.f);
                } else {
                    int fo = co * 121 + yy * 11 + xx;
                    F[fo] = fmaxf(fmaf(0.1f, v, G2[fo]), 0.f);
                }
            }
        }
    };

    #pragma unroll
    for (int rb = 0; rb < 4; ++rb) {
        do_conv(P0, 2 * rb, 0);
        do_conv(P1, 2 * rb + 1, 1);
    }
    do_conv(P0, 8, 2);
    __syncthreads();

    if (t < 88) {
        int tco = t / 11, tyy = t - tco * 11;
        float s = 0.f;
        #pragma unroll
        for (int xx = 0; xx < 11; ++xx) s += F[tco * 121 + tyy * 11 + xx];
        rowsum[t] = s;
    }
    __syncthreads();
    if (t < 8) {
        float s = 0.f;
        #pragma unroll
        for (int j = 0; j < 11; ++j) s += rowsum[t * 11 + j];
        inv[t] = 1.f / s;
    }
    __syncthreads();
    for (int o = t; o < 968; o += 384)
        pa.out[n * 968 + o] = F[o] * inv[o / 121];
}

extern "C" void kernel_launch(void* const* d_in, const int* in_sizes, int n_in,
                              void* d_out, int out_size, void* d_ws, size_t ws_size,
                              hipStream_t stream) {
    const float* x = (const float*)d_in[0];
    const float* y = (const float*)d_in[1];
    const float* k = (const float*)d_in[2];
    const float* gamma = (const float*)d_in[4];

    const size_t xpad_fl = (size_t)64 * 256 * XPROW;
    const size_t e2_fl = (size_t)8 * 131072;
    const size_t need = (xpad_fl + e2_fl + 7744) * sizeof(float);

    float* G;
    if (ws_size >= need) {
        float* xpad = (float*)d_ws;
        float* E2 = xpad + xpad_fl;
        G = E2 + e2_fl;
        pad_kernel<<<256, 256, 0, stream>>>(x, xpad);
        blur_kernel<<<512, 256, 0, stream>>>(xpad, y, k, E2);
        grad_kernel<<<704, 256, 0, stream>>>(xpad, E2, G);
    } else {
        float* E2 = (float*)d_ws;
        G = E2 + e2_fl;
        blur_kernel_ref<<<1024, 256, 0, stream>>>(x, y, k, E2);
        grad_kernel_ref<<<704, 256, 0, stream>>>(x, E2, G);
    }

    PArgs pa;
    for (int i = 0; i < 9; ++i) {
        pa.W[i] = (const float*)d_in[5 + 2 * i];
        pa.B[i] = (const float*)d_in[6 + 2 * i];
    }
    pa.k = k;
    pa.gamma = gamma;
    pa.G = G;
    pa.out = (float*)d_out;
    pronet_kernel<<<8, 384, 0, stream>>>(pa);
}

// Round 7
// 181.920 us; speedup vs baseline: 1.0425x; 1.0425x over previous
//
#include <hip/hip_runtime.h>

// MTFNet: N=8, C=8, H=W=256, L=11, SF=2, h=w=128
// Pipeline:
//  K0: xpad[nc][256][272] = column-reflect-padded x (halo 8 each side); also zeros G
//  K1: E2[n][c'][p] = (blur(x,k) - y), flat reinterpret (p*8+c' = flat(C,h,w)); 4 ps/thread
//  K2: G[n][ki*11+kj][c] += partial contraction; pr-range split in 2 (TLP), atomicAdd combine
//  K3: per-n pronet (9 convs) on G_K = k - 0.1*gamma*G (flat), + normalize (v3)
// Accounting (R1-R6): harness resets ~133us of dur_us. R6 lesson: these kernels are
// TLP-bound — 8-wide/512-block blur regressed 15us; keep 1024 blocks / 4-wide.

__device__ __forceinline__ int refl(int m) {
    m = (m < 0) ? -m : m;
    return (m > 255) ? (510 - m) : m;
}

#define XPROW 272   // 256 + 8 halo each side

// ---------------- K0: column-pad x with reflection; zero G ----------------
__global__ __launch_bounds__(256) void pad_kernel(
        const float* __restrict__ x, float* __restrict__ xp, float* __restrict__ G) {
    int bid = blockIdx.x;
    int chunk = bid & 3;
    int nc = bid >> 2;
    int team = threadIdx.x >> 6;
    int lane = threadIdx.x & 63;
    if (bid == 0) {
        for (int i = threadIdx.x; i < 7744; i += 256) G[i] = 0.f;
    }
    const float* xb = x + nc * 65536;
    float* xpb = xp + nc * (256 * XPROW);
    for (int it = 0; it < 16; ++it) {
        int row = chunk * 64 + it * 4 + team;
        const float* src = xb + row * 256;
        float* dst = xpb + row * XPROW + 8;
        float4 v = reinterpret_cast<const float4*>(src)[lane];
        reinterpret_cast<float4*>(dst)[lane] = v;
        if (lane < 8) {
            dst[-1 - lane] = src[1 + lane];
        } else if (lane < 16) {
            int j = lane - 8;
            dst[256 + j] = src[254 - j];
        }
    }
}

// ---------------- K1: blur + subtract y, store transposed E2 (4 ps/thread) --
// grid = 64 nc * 16 rowblk = 1024 blocks, 256 threads (R4/R5 proven config)
__global__ __launch_bounds__(256) void blur_kernel(
        const float* __restrict__ xp, const float* __restrict__ y,
        const float* __restrict__ kk, float* __restrict__ E2) {
    __shared__ float kl[121];
    int bid = blockIdx.x;
    int rowblk = bid & 15;
    int nc = bid >> 4;
    int t = threadIdx.x;
    if (t < 121) kl[t] = kk[nc * 121 + t];
    __syncthreads();
    int r = rowblk * 8 + (t >> 5);
    int ps0 = (t & 31) * 4;
    const float* xb = xp + nc * (256 * XPROW);
    float a0 = 0.f, a1 = 0.f, a2 = 0.f, a3 = 0.f;
    #pragma unroll
    for (int i = 0; i < 11; ++i) {
        int iy = refl(2 * r - 5 + i);
        const float4* row4 = reinterpret_cast<const float4*>(xb + iy * XPROW + 2 * ps0);
        float w[24];
        #pragma unroll
        for (int q = 0; q < 6; ++q) {
            float4 v = row4[q];
            w[4 * q] = v.x; w[4 * q + 1] = v.y; w[4 * q + 2] = v.z; w[4 * q + 3] = v.w;
        }
        #pragma unroll
        for (int j = 0; j < 11; ++j) {
            float kv = kl[i * 11 + j];
            a0 = fmaf(w[j + 3], kv, a0);
            a1 = fmaf(w[j + 5], kv, a1);
            a2 = fmaf(w[j + 7], kv, a2);
            a3 = fmaf(w[j + 9], kv, a3);
        }
    }
    int n = nc >> 3;
    int o = nc * 16384 + r * 128 + ps0;
    float4 yv = *reinterpret_cast<const float4*>(y + o);
    float e[4] = {a0 - yv.x, a1 - yv.y, a2 - yv.z, a3 - yv.w};
    int qn = o - n * 131072;
    int p = qn >> 3;
    int cbase = qn & 7;
    float* eb = E2 + n * 131072 + p;
    #pragma unroll
    for (int qq = 0; qq < 4; ++qq)
        eb[(cbase + qq) * 16384] = e[qq];
}

// ---------------- K2: G contraction, pr-split x2 for TLP ----------------
// grid = 64 nc * 11 ki * 2 halves = 1408 blocks; each handles 64 pr rows.
// Combine via atomicAdd (G zeroed in pad_kernel).
__global__ __launch_bounds__(256) void grad_kernel(
        const float* __restrict__ xp, const float* __restrict__ E2,
        float* __restrict__ G) {
    int bid = blockIdx.x;
    int ki = bid % 11;
    int rest = bid / 11;
    int half = rest & 1;
    int nc = rest >> 1;
    int n = nc >> 3, c = nc & 7;
    const float* xb = xp + nc * (256 * XPROW);
    const float* Eb = E2 + n * 131072 + c * 16384;
    int t = threadIdx.x;
    int ps0 = (t & 31) * 4;
    int pr0 = t >> 5;
    float acc[11];
    #pragma unroll
    for (int j = 0; j < 11; ++j) acc[j] = 0.f;
    #pragma unroll
    for (int it = 0; it < 8; ++it) {
        int pr = half * 64 + (it << 3) + pr0;
        int iy = refl(ki + 2 * pr - 5);
        float4 ev = *reinterpret_cast<const float4*>(Eb + pr * 128 + ps0);
        const float4* row4 = reinterpret_cast<const float4*>(xb + iy * XPROW + 2 * ps0);
        float w[24];
        #pragma unroll
        for (int q = 0; q < 6; ++q) {
            float4 v = row4[q];
            w[4 * q] = v.x; w[4 * q + 1] = v.y; w[4 * q + 2] = v.z; w[4 * q + 3] = v.w;
        }
        #pragma unroll
        for (int j = 0; j < 11; ++j) {
            float v = acc[j];
            v = fmaf(w[j + 3], ev.x, v);
            v = fmaf(w[j + 5], ev.y, v);
            v = fmaf(w[j + 7], ev.z, v);
            v = fmaf(w[j + 9], ev.w, v);
            acc[j] = v;
        }
    }
    __shared__ float part[4][11];
    int lane = t & 63, wid = t >> 6;
    #pragma unroll
    for (int j = 0; j < 11; ++j) {
        float v = acc[j];
        #pragma unroll
        for (int off = 32; off > 0; off >>= 1)
            v += __shfl_down(v, off, 64);
        if (lane == 0) part[wid][j] = v;
    }
    __syncthreads();
    if (t < 11) {
        float s = part[0][t] + part[1][t] + part[2][t] + part[3][t];
        atomicAdd(&G[n * 968 + (ki * 11 + t) * 8 + c], s * (1.0f / 16384.0f));
    }
}

// ---------------- Fallback kernels (R3, scalar loads, known-good) ----------
__global__ __launch_bounds__(256) void blur_kernel_ref(
        const float* __restrict__ x, const float* __restrict__ y,
        const float* __restrict__ kk, float* __restrict__ E2) {
    __shared__ float kl[121];
    int bid = blockIdx.x;
    int rowblk = bid & 15;
    int nc = bid >> 4;
    int t = threadIdx.x;
    if (t < 121) kl[t] = kk[nc * 121 + t];
    __syncthreads();
    int r = rowblk * 8 + (t >> 5);
    int ps0 = (t & 31) * 4;
    const float* xb = x + nc * 65536;
    float a0 = 0.f, a1 = 0.f, a2 = 0.f, a3 = 0.f;
    int cb = 2 * ps0 - 5;
    #pragma unroll
    for (int i = 0; i < 11; ++i) {
        int iy = refl(2 * r - 5 + i);
        const float* row = xb + iy * 256;
        float c[17];
        #pragma unroll
        for (int u = 0; u < 17; ++u) c[u] = row[refl(cb + u)];
        #pragma unroll
        for (int j = 0; j < 11; ++j) {
            float kv = kl[i * 11 + j];
            a0 = fmaf(c[j], kv, a0);
            a1 = fmaf(c[j + 2], kv, a1);
            a2 = fmaf(c[j + 4], kv, a2);
            a3 = fmaf(c[j + 6], kv, a3);
        }
    }
    int n = nc >> 3;
    int o = nc * 16384 + r * 128 + ps0;
    float4 yv = *reinterpret_cast<const float4*>(y + o);
    float e[4] = {a0 - yv.x, a1 - yv.y, a2 - yv.z, a3 - yv.w};
    int qn = o - n * 131072;
    int p = qn >> 3;
    int cbase = qn & 7;
    float* eb = E2 + n * 131072 + p;
    #pragma unroll
    for (int qq = 0; qq < 4; ++qq)
        eb[(cbase + qq) * 16384] = e[qq];
}

__global__ __launch_bounds__(256) void grad_kernel_ref(
        const float* __restrict__ x, const float* __restrict__ E2,
        float* __restrict__ G) {
    int bid = blockIdx.x;
    int ki = bid % 11;
    int nc = bid / 11;
    int n = nc >> 3, c = nc & 7;
    const float* xb = x + nc * 65536;
    const float* Eb = E2 + n * 131072 + c * 16384;
    int t = threadIdx.x;
    int ps0 = (t & 31) * 4;
    int pr0 = t >> 5;
    int cb = 2 * ps0 - 5;
    float acc[11];
    #pragma unroll
    for (int j = 0; j < 11; ++j) acc[j] = 0.f;
    for (int it = 0; it < 16; ++it) {
        int pr = pr0 + (it << 3);
        int iy = refl(ki + 2 * pr - 5);
        const float* row = xb + iy * 256;
        float cbuf[17];
        #pragma unroll
        for (int u = 0; u < 17; ++u) cbuf[u] = row[refl(cb + u)];
        float4 ev = *reinterpret_cast<const float4*>(Eb + pr * 128 + ps0);
        #pragma unroll
        for (int j = 0; j < 11; ++j) {
            float v = acc[j];
            v = fmaf(cbuf[j], ev.x, v);
            v = fmaf(cbuf[j + 2], ev.y, v);
            v = fmaf(cbuf[j + 4], ev.z, v);
            v = fmaf(cbuf[j + 6], ev.w, v);
            acc[j] = v;
        }
    }
    __shared__ float part[4][11];
    int lane = t & 63, wid = t >> 6;
    #pragma unroll
    for (int j = 0; j < 11; ++j) {
        float v = acc[j];
        #pragma unroll
        for (int off = 32; off > 0; off >>= 1)
            v += __shfl_down(v, off, 64);
        if (lane == 0) part[wid][j] = v;
    }
    __syncthreads();
    if (t < 11) {
        float s = part[0][t] + part[1][t] + part[2][t] + part[3][t];
        G[n * 968 + (ki * 11 + t) * 8 + c] = s * (1.0f / 16384.0f);
    }
}

// ---------------- K3: pronet v3 ----------------
struct PArgs {
    const float* W[9];
    const float* B[9];
    const float* k;
    const float* gamma;
    const float* G;
    float* out;
};

#define PLSTRIDE 20
#define WSTRIDE 12

__global__ __launch_bounds__(384) void pronet_kernel(PArgs pa) {
    __shared__ __align__(16) float P0[8 * 13 * PLSTRIDE];
    __shared__ __align__(16) float P1[8 * 13 * PLSTRIDE];
    __shared__ float G2[968];
    __shared__ float F[968];
    __shared__ __align__(16) float red[3 * 88 * WSTRIDE];
    __shared__ __align__(16) float wts[9 * 64 * WSTRIDE];
    __shared__ float bs[9 * 8];
    __shared__ float rowsum[88];
    __shared__ float inv[8];

    int n = blockIdx.x;
    int t = threadIdx.x;

    #pragma unroll
    for (int widx = 0; widx < 9; ++widx) {
        const float* wsrc = pa.W[widx];
        for (int i = t; i < 576; i += 384) {
            int oc = i / 9, q = i - oc * 9;
            wts[(widx * 64 + oc) * WSTRIDE + q] = wsrc[i];
        }
        if (t < 8) bs[widx * 8 + t] = pa.B[widx][t];
    }
    for (int i = t; i < 8 * 13 * PLSTRIDE; i += 384) { P0[i] = 0.f; P1[i] = 0.f; }
    __syncthreads();

    float gm = pa.gamma[0] * 0.1f;
    for (int o = t; o < 968; o += 384) {
        float v = pa.k[n * 968 + o] - gm * pa.G[n * 968 + o];
        G2[o] = v;
        int co = o / 121, rem = o - co * 121;
        int yy = rem / 11, xx = rem - yy * 11;
        P0[(co * 13 + yy + 1) * PLSTRIDE + xx + 1] = v;
    }

    bool active = t < 352;
    int quarter = t / 88;
    int id = t - quarter * 88;
    int co = id / 11, yy = id - co * 11;
    int ci0 = quarter * 2;

    auto do_conv = [&](const float* Pin, int widx, int mode) {
        __syncthreads();
        float acc[12];
        if (active) {
            #pragma unroll
            for (int xx = 0; xx < 12; ++xx) acc[xx] = 0.f;
            #pragma unroll
            for (int cq = 0; cq < 2; ++cq) {
                int ci = ci0 + cq;
                const float4* wp4 = reinterpret_cast<const float4*>(
                    &wts[(widx * 64 + co * 8 + ci) * WSTRIDE]);
                float4 w0 = wp4[0], w1 = wp4[1], w2 = wp4[2];
                float wv[9] = {w0.x, w0.y, w0.z, w0.w, w1.x, w1.y, w1.z, w1.w, w2.x};
                float r[3][13];
                #pragma unroll
                for (int dy = 0; dy < 3; ++dy) {
                    const float* row = Pin + (ci * 13 + yy + dy) * PLSTRIDE;
                    float4 a = *reinterpret_cast<const float4*>(row);
                    float4 b = *reinterpret_cast<const float4*>(row + 4);
                    float4 c = *reinterpret_cast<const float4*>(row + 8);
                    r[dy][0] = a.x;  r[dy][1] = a.y;  r[dy][2]  = a.z;  r[dy][3]  = a.w;
                    r[dy][4] = b.x;  r[dy][5] = b.y;  r[dy][6]  = b.z;  r[dy][7]  = b.w;
                    r[dy][8] = c.x;  r[dy][9] = c.y;  r[dy][10] = c.z;  r[dy][11] = c.w;
                    r[dy][12] = row[12];
                }
                #pragma unroll
                for (int xx = 0; xx < 11; ++xx) {
                    float v = acc[xx];
                    v = fmaf(r[0][xx],     wv[0], v);
                    v = fmaf(r[0][xx + 1], wv[1], v);
                    v = fmaf(r[0][xx + 2], wv[2], v);
                    v = fmaf(r[1][xx],     wv[3], v);
                    v = fmaf(r[1][xx + 1], wv[4], v);
                    v = fmaf(r[1][xx + 2], wv[5], v);
                    v = fmaf(r[2][xx],     wv[6], v);
                    v = fmaf(r[2][xx + 1], wv[7], v);
                    v = fmaf(r[2][xx + 2], wv[8], v);
                    acc[xx] = v;
                }
            }
            if (quarter != 0) {
                float4* rp = reinterpret_cast<float4*>(
                    &red[((quarter - 1) * 88 + id) * WSTRIDE]);
                rp[0] = make_float4(acc[0], acc[1], acc[2],  acc[3]);
                rp[1] = make_float4(acc[4], acc[5], acc[6],  acc[7]);
                rp[2] = make_float4(acc[8], acc[9], acc[10], acc[11]);
            }
        }
        __syncthreads();
        if (active && quarter == 0) {
            float b = bs[widx * 8 + co];
            float oth[12];
            #pragma unroll
            for (int pq = 0; pq < 3; ++pq) {
                const float4* rp = reinterpret_cast<const float4*>(
                    &red[(pq * 88 + id) * WSTRIDE]);
                float4 v0 = rp[0], v1 = rp[1], v2 = rp[2];
                if (pq == 0) {
                    oth[0] = v0.x; oth[1] = v0.y; oth[2]  = v0.z; oth[3]  = v0.w;
                    oth[4] = v1.x; oth[5] = v1.y; oth[6]  = v1.z; oth[7]  = v1.w;
                    oth[8] = v2.x; oth[9] = v2.y; oth[10] = v2.z; oth[11] = v2.w;
                } else {
                    oth[0] += v0.x; oth[1] += v0.y; oth[2]  += v0.z; oth[3]  += v0.w;
                    oth[4] += v1.x; oth[5] += v1.y; oth[6]  += v1.z; oth[7]  += v1.w;
                    oth[8] += v2.x; oth[9] += v2.y; oth[10] += v2.z; oth[11] += v2.w;
                }
            }
            #pragma unroll
            for (int xx = 0; xx < 11; ++xx) {
                float v = acc[xx] + oth[xx] + b;
                int pidx = (co * 13 + yy + 1) * PLSTRIDE + xx + 1;
                if (mode == 0) {
                    P1[pidx] = fmaxf(v, 0.f);
                } else if (mode == 1) {
                    float p = P0[pidx];
                    P0[pidx] = fmaxf(fmaf(0.1f, v, p), 0.f);
                } else {
                    int fo = co * 121 + yy * 11 + xx;
                    F[fo] = fmaxf(fmaf(0.1f, v, G2[fo]), 0.f);
                }
            }
        }
    };

    #pragma unroll
    for (int rb = 0; rb < 4; ++rb) {
        do_conv(P0, 2 * rb, 0);
        do_conv(P1, 2 * rb + 1, 1);
    }
    do_conv(P0, 8, 2);
    __syncthreads();

    if (t < 88) {
        int tco = t / 11, tyy = t - tco * 11;
        float s = 0.f;
        #pragma unroll
        for (int xx = 0; xx < 11; ++xx) s += F[tco * 121 + tyy * 11 + xx];
        rowsum[t] = s;
    }
    __syncthreads();
    if (t < 8) {
        float s = 0.f;
        #pragma unroll
        for (int j = 0; j < 11; ++j) s += rowsum[t * 11 + j];
        inv[t] = 1.f / s;
    }
    __syncthreads();
    for (int o = t; o < 968; o += 384)
        pa.out[n * 968 + o] = F[o] * inv[o / 121];
}

extern "C" void kernel_launch(void* const* d_in, const int* in_sizes, int n_in,
                              void* d_out, int out_size, void* d_ws, size_t ws_size,
                              hipStream_t stream) {
    const float* x = (const float*)d_in[0];
    const float* y = (const float*)d_in[1];
    const float* k = (const float*)d_in[2];
    const float* gamma = (const float*)d_in[4];

    const size_t xpad_fl = (size_t)64 * 256 * XPROW;
    const size_t e2_fl = (size_t)8 * 131072;
    const size_t need = (xpad_fl + e2_fl + 7744) * sizeof(float);

    float* G;
    if (ws_size >= need) {
        float* xpad = (float*)d_ws;
        float* E2 = xpad + xpad_fl;
        G = E2 + e2_fl;
        pad_kernel<<<256, 256, 0, stream>>>(x, xpad, G);
        blur_kernel<<<1024, 256, 0, stream>>>(xpad, y, k, E2);
        grad_kernel<<<1408, 256, 0, stream>>>(xpad, E2, G);
    } else {
        float* E2 = (float*)d_ws;
        G = E2 + e2_fl;
        blur_kernel_ref<<<1024, 256, 0, stream>>>(x, y, k, E2);
        grad_kernel_ref<<<704, 256, 0, stream>>>(x, E2, G);
    }

    PArgs pa;
    for (int i = 0; i < 9; ++i) {
        pa.W[i] = (const float*)d_in[5 + 2 * i];
        pa.B[i] = (const float*)d_in[6 + 2 * i];
    }
    pa.k = k;
    pa.gamma = gamma;
    pa.G = G;
    pa.out = (float*)d_out;
    pronet_kernel<<<8, 384, 0, stream>>>(pa);
}

// Round 8
// 175.282 us; speedup vs baseline: 1.0820x; 1.0379x over previous
//
#include <hip/hip_runtime.h>

// MTFNet: N=8, C=8, H=W=256, L=11, SF=2, h=w=128
// Pipeline:
//  K0: xpad[nc][256][272] = column-reflect-padded x (halo 8 each side)
//  K1: E2[n][c'][p] = (blur(x,k) - y), flat reinterpret (p*8+c' = flat(C,h,w)); 4 ps/thread
//  K2: G[n][ki*11+kj][c] = (1/16384)*sum_p window*E2; 704 blocks, direct store (R5-proven)
//  K3: pronet v4: 704 threads (8-way ci split, 11 waves) — R7 profile showed v3 at ~51us,
//      94% latency bubbles at 1.4 waves/SIMD; v4 doubles waves + halves per-thread work.
// Accounting: harness resets ~100us of dur_us (268MB ws poison + restores) — fixed floor.
// R6 lesson: blur/grad are TLP-bound; keep 1024/704 blocks, 4 ps/thread.

__device__ __forceinline__ int refl(int m) {
    m = (m < 0) ? -m : m;
    return (m > 255) ? (510 - m) : m;
}

#define XPROW 272   // 256 + 8 halo each side

// ---------------- K0: column-pad x with reflection ----------------
__global__ __launch_bounds__(256) void pad_kernel(
        const float* __restrict__ x, float* __restrict__ xp) {
    int bid = blockIdx.x;
    int chunk = bid & 3;
    int nc = bid >> 2;
    int team = threadIdx.x >> 6;
    int lane = threadIdx.x & 63;
    const float* xb = x + nc * 65536;
    float* xpb = xp + nc * (256 * XPROW);
    for (int it = 0; it < 16; ++it) {
        int row = chunk * 64 + it * 4 + team;
        const float* src = xb + row * 256;
        float* dst = xpb + row * XPROW + 8;
        float4 v = reinterpret_cast<const float4*>(src)[lane];
        reinterpret_cast<float4*>(dst)[lane] = v;
        if (lane < 8) {
            dst[-1 - lane] = src[1 + lane];
        } else if (lane < 16) {
            int j = lane - 8;
            dst[256 + j] = src[254 - j];
        }
    }
}

// ---------------- K1: blur + subtract y, store transposed E2 (4 ps/thread) --
// grid = 64 nc * 16 rowblk = 1024 blocks, 256 threads (R4/R5 proven config)
__global__ __launch_bounds__(256) void blur_kernel(
        const float* __restrict__ xp, const float* __restrict__ y,
        const float* __restrict__ kk, float* __restrict__ E2) {
    __shared__ float kl[121];
    int bid = blockIdx.x;
    int rowblk = bid & 15;
    int nc = bid >> 4;
    int t = threadIdx.x;
    if (t < 121) kl[t] = kk[nc * 121 + t];
    __syncthreads();
    int r = rowblk * 8 + (t >> 5);
    int ps0 = (t & 31) * 4;
    const float* xb = xp + nc * (256 * XPROW);
    float a0 = 0.f, a1 = 0.f, a2 = 0.f, a3 = 0.f;
    #pragma unroll
    for (int i = 0; i < 11; ++i) {
        int iy = refl(2 * r - 5 + i);
        const float4* row4 = reinterpret_cast<const float4*>(xb + iy * XPROW + 2 * ps0);
        float w[24];
        #pragma unroll
        for (int q = 0; q < 6; ++q) {
            float4 v = row4[q];
            w[4 * q] = v.x; w[4 * q + 1] = v.y; w[4 * q + 2] = v.z; w[4 * q + 3] = v.w;
        }
        #pragma unroll
        for (int j = 0; j < 11; ++j) {
            float kv = kl[i * 11 + j];
            a0 = fmaf(w[j + 3], kv, a0);
            a1 = fmaf(w[j + 5], kv, a1);
            a2 = fmaf(w[j + 7], kv, a2);
            a3 = fmaf(w[j + 9], kv, a3);
        }
    }
    int n = nc >> 3;
    int o = nc * 16384 + r * 128 + ps0;
    float4 yv = *reinterpret_cast<const float4*>(y + o);
    float e[4] = {a0 - yv.x, a1 - yv.y, a2 - yv.z, a3 - yv.w};
    int qn = o - n * 131072;
    int p = qn >> 3;
    int cbase = qn & 7;
    float* eb = E2 + n * 131072 + p;
    #pragma unroll
    for (int qq = 0; qq < 4; ++qq)
        eb[(cbase + qq) * 16384] = e[qq];
}

// ---------------- K2: G contraction (R5-proven: 704 blocks, direct store) ---
__global__ __launch_bounds__(256) void grad_kernel(
        const float* __restrict__ xp, const float* __restrict__ E2,
        float* __restrict__ G) {
    int bid = blockIdx.x;
    int ki = bid % 11;
    int nc = bid / 11;
    int n = nc >> 3, c = nc & 7;
    const float* xb = xp + nc * (256 * XPROW);
    const float* Eb = E2 + n * 131072 + c * 16384;
    int t = threadIdx.x;
    int ps0 = (t & 31) * 4;
    int pr0 = t >> 5;
    float acc[11];
    #pragma unroll
    for (int j = 0; j < 11; ++j) acc[j] = 0.f;
    for (int it = 0; it < 16; ++it) {
        int pr = pr0 + (it << 3);
        int iy = refl(ki + 2 * pr - 5);
        float4 ev = *reinterpret_cast<const float4*>(Eb + pr * 128 + ps0);
        const float4* row4 = reinterpret_cast<const float4*>(xb + iy * XPROW + 2 * ps0);
        float w[24];
        #pragma unroll
        for (int q = 0; q < 6; ++q) {
            float4 v = row4[q];
            w[4 * q] = v.x; w[4 * q + 1] = v.y; w[4 * q + 2] = v.z; w[4 * q + 3] = v.w;
        }
        #pragma unroll
        for (int j = 0; j < 11; ++j) {
            float v = acc[j];
            v = fmaf(w[j + 3], ev.x, v);
            v = fmaf(w[j + 5], ev.y, v);
            v = fmaf(w[j + 7], ev.z, v);
            v = fmaf(w[j + 9], ev.w, v);
            acc[j] = v;
        }
    }
    __shared__ float part[4][11];
    int lane = t & 63, wid = t >> 6;
    #pragma unroll
    for (int j = 0; j < 11; ++j) {
        float v = acc[j];
        #pragma unroll
        for (int off = 32; off > 0; off >>= 1)
            v += __shfl_down(v, off, 64);
        if (lane == 0) part[wid][j] = v;
    }
    __syncthreads();
    if (t < 11) {
        float s = part[0][t] + part[1][t] + part[2][t] + part[3][t];
        G[n * 968 + (ki * 11 + t) * 8 + c] = s * (1.0f / 16384.0f);
    }
}

// ---------------- Fallback kernels (R3, scalar loads, known-good) ----------
__global__ __launch_bounds__(256) void blur_kernel_ref(
        const float* __restrict__ x, const float* __restrict__ y,
        const float* __restrict__ kk, float* __restrict__ E2) {
    __shared__ float kl[121];
    int bid = blockIdx.x;
    int rowblk = bid & 15;
    int nc = bid >> 4;
    int t = threadIdx.x;
    if (t < 121) kl[t] = kk[nc * 121 + t];
    __syncthreads();
    int r = rowblk * 8 + (t >> 5);
    int ps0 = (t & 31) * 4;
    const float* xb = x + nc * 65536;
    float a0 = 0.f, a1 = 0.f, a2 = 0.f, a3 = 0.f;
    int cb = 2 * ps0 - 5;
    #pragma unroll
    for (int i = 0; i < 11; ++i) {
        int iy = refl(2 * r - 5 + i);
        const float* row = xb + iy * 256;
        float c[17];
        #pragma unroll
        for (int u = 0; u < 17; ++u) c[u] = row[refl(cb + u)];
        #pragma unroll
        for (int j = 0; j < 11; ++j) {
            float kv = kl[i * 11 + j];
            a0 = fmaf(c[j], kv, a0);
            a1 = fmaf(c[j + 2], kv, a1);
            a2 = fmaf(c[j + 4], kv, a2);
            a3 = fmaf(c[j + 6], kv, a3);
        }
    }
    int n = nc >> 3;
    int o = nc * 16384 + r * 128 + ps0;
    float4 yv = *reinterpret_cast<const float4*>(y + o);
    float e[4] = {a0 - yv.x, a1 - yv.y, a2 - yv.z, a3 - yv.w};
    int qn = o - n * 131072;
    int p = qn >> 3;
    int cbase = qn & 7;
    float* eb = E2 + n * 131072 + p;
    #pragma unroll
    for (int qq = 0; qq < 4; ++qq)
        eb[(cbase + qq) * 16384] = e[qq];
}

__global__ __launch_bounds__(256) void grad_kernel_ref(
        const float* __restrict__ x, const float* __restrict__ E2,
        float* __restrict__ G) {
    int bid = blockIdx.x;
    int ki = bid % 11;
    int nc = bid / 11;
    int n = nc >> 3, c = nc & 7;
    const float* xb = x + nc * 65536;
    const float* Eb = E2 + n * 131072 + c * 16384;
    int t = threadIdx.x;
    int ps0 = (t & 31) * 4;
    int pr0 = t >> 5;
    int cb = 2 * ps0 - 5;
    float acc[11];
    #pragma unroll
    for (int j = 0; j < 11; ++j) acc[j] = 0.f;
    for (int it = 0; it < 16; ++it) {
        int pr = pr0 + (it << 3);
        int iy = refl(ki + 2 * pr - 5);
        const float* row = xb + iy * 256;
        float cbuf[17];
        #pragma unroll
        for (int u = 0; u < 17; ++u) cbuf[u] = row[refl(cb + u)];
        float4 ev = *reinterpret_cast<const float4*>(Eb + pr * 128 + ps0);
        #pragma unroll
        for (int j = 0; j < 11; ++j) {
            float v = acc[j];
            v = fmaf(cbuf[j], ev.x, v);
            v = fmaf(cbuf[j + 2], ev.y, v);
            v = fmaf(cbuf[j + 4], ev.z, v);
            v = fmaf(cbuf[j + 6], ev.w, v);
            acc[j] = v;
        }
    }
    __shared__ float part[4][11];
    int lane = t & 63, wid = t >> 6;
    #pragma unroll
    for (int j = 0; j < 11; ++j) {
        float v = acc[j];
        #pragma unroll
        for (int off = 32; off > 0; off >>= 1)
            v += __shfl_down(v, off, 64);
        if (lane == 0) part[wid][j] = v;
    }
    __syncthreads();
    if (t < 11) {
        float s = part[0][t] + part[1][t] + part[2][t] + part[3][t];
        G[n * 968 + (ki * 11 + t) * 8 + c] = s * (1.0f / 16384.0f);
    }
}

// ---------------- K3: pronet v4 ----------------
// 704 threads = 11 waves: g = t/88 picks ci (0..7), id = t%88 -> (co, yy).
// Each thread computes a 1-ci partial row of 11; groups 1..7 write partials
// (b128) to red; group 0 combines 7 partials + bias and writes output.
// NOTE: launch MUST be 704 threads (== __launch_bounds__); mismatch no-ops (R2).
struct PArgs {
    const float* W[9];
    const float* B[9];
    const float* k;
    const float* gamma;
    const float* G;
    float* out;
};

#define PLSTRIDE 20
#define WSTRIDE 12

__global__ __launch_bounds__(704) void pronet_kernel(PArgs pa) {
    __shared__ __align__(16) float P0[8 * 13 * PLSTRIDE];
    __shared__ __align__(16) float P1[8 * 13 * PLSTRIDE];
    __shared__ float G2[968];
    __shared__ float F[968];
    __shared__ __align__(16) float red[7 * 88 * WSTRIDE];
    __shared__ __align__(16) float wts[9 * 64 * WSTRIDE];
    __shared__ float bs[9 * 8];
    __shared__ float rowsum[88];
    __shared__ float inv[8];

    int n = blockIdx.x;
    int t = threadIdx.x;

    // stage weights padded: wts[(widx*64 + co*8+ci)*12 + q] = W[widx][(co*8+ci)*9 + q]
    #pragma unroll
    for (int widx = 0; widx < 9; ++widx) {
        const float* wsrc = pa.W[widx];
        if (t < 576) {
            int oc = t / 9, q = t - oc * 9;
            wts[(widx * 64 + oc) * WSTRIDE + q] = wsrc[t];
        }
        if (t < 8) bs[widx * 8 + t] = pa.B[widx][t];
    }
    for (int i = t; i < 8 * 13 * PLSTRIDE; i += 704) { P0[i] = 0.f; P1[i] = 0.f; }
    __syncthreads();

    float gm = pa.gamma[0] * 0.1f;
    for (int o = t; o < 968; o += 704) {
        // G_K flat reinterpretation: elementwise in flat order
        float v = pa.k[n * 968 + o] - gm * pa.G[n * 968 + o];
        G2[o] = v;
        int co = o / 121, rem = o - co * 121;
        int yy = rem / 11, xx = rem - yy * 11;
        P0[(co * 13 + yy + 1) * PLSTRIDE + xx + 1] = v;
    }

    int g = t / 88;              // ci group 0..7
    int id = t - g * 88;         // 0..87
    int co = id / 11, yy = id - co * 11;
    int ci = g;

    // mode 0: P1 = relu(conv);  mode 1: P0 = relu(P0 + 0.1*conv);
    // mode 2: F  = relu(G2 + 0.1*conv)
    auto do_conv = [&](const float* Pin, int widx, int mode) {
        __syncthreads();
        float acc[12];
        {
            const float4* wp4 = reinterpret_cast<const float4*>(
                &wts[(widx * 64 + co * 8 + ci) * WSTRIDE]);
            float4 w0 = wp4[0], w1 = wp4[1], w2 = wp4[2];
            float wv[9] = {w0.x, w0.y, w0.z, w0.w, w1.x, w1.y, w1.z, w1.w, w2.x};
            float r[3][13];
            #pragma unroll
            for (int dy = 0; dy < 3; ++dy) {
                const float* row = Pin + (ci * 13 + yy + dy) * PLSTRIDE;
                float4 a = *reinterpret_cast<const float4*>(row);
                float4 b = *reinterpret_cast<const float4*>(row + 4);
                float4 c = *reinterpret_cast<const float4*>(row + 8);
                r[dy][0] = a.x;  r[dy][1] = a.y;  r[dy][2]  = a.z;  r[dy][3]  = a.w;
                r[dy][4] = b.x;  r[dy][5] = b.y;  r[dy][6]  = b.z;  r[dy][7]  = b.w;
                r[dy][8] = c.x;  r[dy][9] = c.y;  r[dy][10] = c.z;  r[dy][11] = c.w;
                r[dy][12] = row[12];
            }
            #pragma unroll
            for (int xx = 0; xx < 11; ++xx) {
                float v = 0.f;
                v = fmaf(r[0][xx],     wv[0], v);
                v = fmaf(r[0][xx + 1], wv[1], v);
                v = fmaf(r[0][xx + 2], wv[2], v);
                v = fmaf(r[1][xx],     wv[3], v);
                v = fmaf(r[1][xx + 1], wv[4], v);
                v = fmaf(r[1][xx + 2], wv[5], v);
                v = fmaf(r[2][xx],     wv[6], v);
                v = fmaf(r[2][xx + 1], wv[7], v);
                v = fmaf(r[2][xx + 2], wv[8], v);
                acc[xx] = v;
            }
            acc[11] = 0.f;
            if (g != 0) {
                float4* rp = reinterpret_cast<float4*>(
                    &red[((g - 1) * 88 + id) * WSTRIDE]);
                rp[0] = make_float4(acc[0], acc[1], acc[2],  acc[3]);
                rp[1] = make_float4(acc[4], acc[5], acc[6],  acc[7]);
                rp[2] = make_float4(acc[8], acc[9], acc[10], acc[11]);
            }
        }
        __syncthreads();
        if (g == 0) {
            float b = bs[widx * 8 + co];
            float oth[12];
            #pragma unroll
            for (int pq = 0; pq < 7; ++pq) {
                const float4* rp = reinterpret_cast<const float4*>(
                    &red[(pq * 88 + id) * WSTRIDE]);
                float4 v0 = rp[0], v1 = rp[1], v2 = rp[2];
                if (pq == 0) {
                    oth[0] = v0.x; oth[1] = v0.y; oth[2]  = v0.z; oth[3]  = v0.w;
                    oth[4] = v1.x; oth[5] = v1.y; oth[6]  = v1.z; oth[7]  = v1.w;
                    oth[8] = v2.x; oth[9] = v2.y; oth[10] = v2.z; oth[11] = v2.w;
                } else {
                    oth[0] += v0.x; oth[1] += v0.y; oth[2]  += v0.z; oth[3]  += v0.w;
                    oth[4] += v1.x; oth[5] += v1.y; oth[6]  += v1.z; oth[7]  += v1.w;
                    oth[8] += v2.x; oth[9] += v2.y; oth[10] += v2.z; oth[11] += v2.w;
                }
            }
            #pragma unroll
            for (int xx = 0; xx < 11; ++xx) {
                float v = acc[xx] + oth[xx] + b;
                int pidx = (co * 13 + yy + 1) * PLSTRIDE + xx + 1;
                if (mode == 0) {
                    P1[pidx] = fmaxf(v, 0.f);
                } else if (mode == 1) {
                    float p = P0[pidx];
                    P0[pidx] = fmaxf(fmaf(0.1f, v, p), 0.f);
                } else {
                    int fo = co * 121 + yy * 11 + xx;
                    F[fo] = fmaxf(fmaf(0.1f, v, G2[fo]), 0.f);
                }
            }
        }
    };

    #pragma unroll
    for (int rb = 0; rb < 4; ++rb) {
        do_conv(P0, 2 * rb, 0);
        do_conv(P1, 2 * rb + 1, 1);
    }
    do_conv(P0, 8, 2);
    __syncthreads();

    if (t < 88) {
        int tco = t / 11, tyy = t - tco * 11;
        float s = 0.f;
        #pragma unroll
        for (int xx = 0; xx < 11; ++xx) s += F[tco * 121 + tyy * 11 + xx];
        rowsum[t] = s;
    }
    __syncthreads();
    if (t < 8) {
        float s = 0.f;
        #pragma unroll
        for (int j = 0; j < 11; ++j) s += rowsum[t * 11 + j];
        inv[t] = 1.f / s;
    }
    __syncthreads();
    for (int o = t; o < 968; o += 704)
        pa.out[n * 968 + o] = F[o] * inv[o / 121];
}

extern "C" void kernel_launch(void* const* d_in, const int* in_sizes, int n_in,
                              void* d_out, int out_size, void* d_ws, size_t ws_size,
                              hipStream_t stream) {
    const float* x = (const float*)d_in[0];
    const float* y = (const float*)d_in[1];
    const float* k = (const float*)d_in[2];
    const float* gamma = (const float*)d_in[4];

    const size_t xpad_fl = (size_t)64 * 256 * XPROW;
    const size_t e2_fl = (size_t)8 * 131072;
    const size_t need = (xpad_fl + e2_fl + 7744) * sizeof(float);

    float* G;
    if (ws_size >= need) {
        float* xpad = (float*)d_ws;
        float* E2 = xpad + xpad_fl;
        G = E2 + e2_fl;
        pad_kernel<<<256, 256, 0, stream>>>(x, xpad);
        blur_kernel<<<1024, 256, 0, stream>>>(xpad, y, k, E2);
        grad_kernel<<<704, 256, 0, stream>>>(xpad, E2, G);
    } else {
        float* E2 = (float*)d_ws;
        G = E2 + e2_fl;
        blur_kernel_ref<<<1024, 256, 0, stream>>>(x, y, k, E2);
        grad_kernel_ref<<<704, 256, 0, stream>>>(x, E2, G);
    }

    PArgs pa;
    for (int i = 0; i < 9; ++i) {
        pa.W[i] = (const float*)d_in[5 + 2 * i];
        pa.B[i] = (const float*)d_in[6 + 2 * i];
    }
    pa.k = k;
    pa.gamma = gamma;
    pa.G = G;
    pa.out = (float*)d_out;
    pronet_kernel<<<8, 704, 0, stream>>>(pa);
}